// Round 4
// baseline (270.024 us; speedup 1.0000x reference)
//
#include <hip/hip_runtime.h>
#include <hip/hip_bf16.h>

// out[t,b,i,e] = x[t,b,i] * W[i,e] + b[e]
// T=8, B=64, D=512, E=256, fp32. Output 256 MiB -> pure write-stream kernel.
//
// Each thread owns a fixed (i, e4) pair; W/b register-resident.
// Two-phase body: (1) issue all 32 x-loads (independent, all in flight),
// (2) pure FMA + nontemporal-store stream with no load dependence.
// 16 slices x 512 i x 64 e4 = 524288 threads = 2048 blocks x 256
// = 8 blocks/CU = 32 waves/CU (full occupancy at ~50 VGPR).

#define DD   512          // D
#define E4   64           // E/4
#define NROW 512          // T*B
#define SLICES 16
#define RPT  (NROW / SLICES)   // 32 rows per thread

typedef float vfloat4 __attribute__((ext_vector_type(4)));

__global__ __launch_bounds__(256) void dense_embed_kernel(
    const float*  __restrict__ x,    // (NROW, D)
    const float4* __restrict__ W,    // (D, E4)
    const float4* __restrict__ b,    // (E4)
    float4*       __restrict__ out)  // (NROW*D, E4)
{
    const int gtid  = blockIdx.x * 256 + threadIdx.x;
    const int e4    = gtid & (E4 - 1);
    const int i     = (gtid >> 6) & (DD - 1);
    const int slice = gtid >> 15;            // 0..15

    const float4 w  = W[(i << 6) | e4];      // register-resident
    const float4 bb = b[e4];

    const int r0 = slice * RPT;
    const float* xp = x + r0 * DD + i;                       // wave-uniform addr

    // Phase 1: all 32 x loads in flight (independent addresses).
    float xs[RPT];
    #pragma unroll
    for (int k = 0; k < RPT; ++k) xs[k] = xp[k * DD];

    // Phase 2: pure compute + nt-store stream.
    float4* op = out + ((size_t)(r0 * DD + i) << 6) + e4;    // lane-consecutive
    #pragma unroll
    for (int k = 0; k < RPT; ++k) {
        const float xv = xs[k];
        vfloat4 o;
        o.x = fmaf(xv, w.x, bb.x);
        o.y = fmaf(xv, w.y, bb.y);
        o.z = fmaf(xv, w.z, bb.z);
        o.w = fmaf(xv, w.w, bb.w);
        __builtin_nontemporal_store(o, (vfloat4*)op);  // global_store_dwordx4 nt
        op += (size_t)DD * E4;
    }
}

extern "C" void kernel_launch(void* const* d_in, const int* in_sizes, int n_in,
                              void* d_out, int out_size, void* d_ws, size_t ws_size,
                              hipStream_t stream) {
    const float*  x = (const float*)d_in[0];
    const float4* W = (const float4*)d_in[1];
    const float4* b = (const float4*)d_in[2];
    float4* out = (float4*)d_out;

    dense_embed_kernel<<<2048, 256, 0, stream>>>(x, W, b, out);
}